// Round 2
// baseline (452.762 us; speedup 1.0000x reference)
//
#include <hip/hip_runtime.h>
#include <hip/hip_bf16.h>
#include <math.h>

// Problem constants
#define CDIM 256
#define HW   1024          // 32*32
#define NVEC 32768         // B*H*W
#define NE   1024
#define ZSIZE 8388608      // 32*256*32*32
#define NSPLIT 8           // codebook j-splits (128 codes each)

// Output layout (floats): [loss(1)][z_q(ZSIZE)][perp(1)][idx(NVEC)][z_q1(ZSIZE)]
#define OUT_LOSS 0
#define OUT_ZQ   1
#define OUT_PERP 8388609
#define OUT_IDX  8388610
#define OUT_ZQ1  8421378

// Workspace layout (bytes)
#define WS_HIST   64                    // 1024 ints
#define WS_ENORM  8192                  // 1024 floats
#define WS_IDX    16384                 // 32768 ints (final idx)
#define WS_SCORE  147456                // 8*32768 floats (per-split best score)
#define WS_IDXP   1196032               // 8*32768 ints  (per-split best idx)

// ---------------- codebook norms: ||e_j||^2 ----------------
__global__ __launch_bounds__(256) void vq_enorm(const float* __restrict__ emb,
                                                float* __restrict__ enorm) {
    int code = blockIdx.x * 4 + (threadIdx.x >> 6);
    int lane = threadIdx.x & 63;
    float4 v = *(const float4*)(emb + (size_t)code * CDIM + lane * 4);
    float s = v.x * v.x + v.y * v.y + v.z * v.z + v.w * v.w;
    for (int off = 32; off; off >>= 1) s += __shfl_down(s, off, 64);
    if (lane == 0) enorm[code] = s;
}

// ---------------- fused distance-GEMM + per-split argmax ----------------
// score(n,j) = z_n . e_j - 0.5*||e_j||^2  (argmax == argmin of distance)
// Block: BM=128 rows x 128-code split, BK=32, 256 threads, 8x8 micro-tile.
// zs: [k][n] (no transpose needed, z global is channel-major)
// es: [j][k] row-major (no transpose -> contiguous b128 staging writes),
//     k-quad XOR-swizzled by (j>>3)&7 so fixed-k reads spread banks.
__global__ __launch_bounds__(256, 3) void vq_argmin(
    const float* __restrict__ z, const float* __restrict__ emb,
    const float* __restrict__ enorm,
    float* __restrict__ score_ws, int* __restrict__ idxp_ws)
{
    __shared__ float zs[32 * 128];   // 16 KB, [k][n] stride 128
    __shared__ float es[128 * 32];   // 16 KB, [j][k] stride 32 (swizzled k-quads)

    const int tid = threadIdx.x;
    const int tn  = tid & 15;        // rows tn*8 .. tn*8+7
    const int tj  = tid >> 4;        // cols tj*8 .. tj*8+7
    const int mtile = blockIdx.x & 255;
    const int js    = blockIdx.x >> 8;          // 0..7
    const int n0 = mtile << 7;                  // 128-row tile (never crosses image)
    const int b_img = n0 >> 10, hw0 = n0 & 1023;
    const float* zb = z + (size_t)b_img * (CDIM * HW) + hw0;
    const int j0 = js << 7;
    const int swz = tj & 7;

    float acc[8][8];
#pragma unroll
    for (int a = 0; a < 8; ++a)
#pragma unroll
        for (int b = 0; b < 8; ++b) acc[a][b] = 0.f;

    for (int k0 = 0; k0 < CDIM; k0 += 32) {
        __syncthreads();
        // stage z tile: 32 k-rows x 128 n (coalesced, contiguous LDS writes)
#pragma unroll
        for (int r = 0; r < 4; ++r) {
            int u = r * 256 + tid;
            int krow = u >> 5;          // 0..31
            int c4   = u & 31;          // float4 col
            float4 v = *(const float4*)(zb + (size_t)(k0 + krow) * HW + c4 * 4);
            *(float4*)(zs + krow * 128 + c4 * 4) = v;
        }
        // stage e tile: 128 j x 32 k, row-major, swizzled k-quad within row
#pragma unroll
        for (int r = 0; r < 4; ++r) {
            int u = r * 256 + tid;
            int j  = u >> 3;            // 0..127
            int c4 = u & 7;             // k-quad
            float4 v = *(const float4*)(emb + (size_t)(j0 + j) * CDIM + k0 + c4 * 4);
            *(float4*)(es + j * 32 + ((c4 ^ ((j >> 3) & 7)) << 2)) = v;
        }
        __syncthreads();

#pragma unroll 2
        for (int kk = 0; kk < 32; kk += 4) {
            const int eoff = (((kk >> 2) ^ swz) << 2);
            float ev[8][4];
#pragma unroll
            for (int b = 0; b < 8; ++b) {
                float4 v = *(const float4*)(es + (tj * 8 + b) * 32 + eoff);
                ev[b][0] = v.x; ev[b][1] = v.y; ev[b][2] = v.z; ev[b][3] = v.w;
            }
            float zr[4][8];
#pragma unroll
            for (int t = 0; t < 4; ++t) {
                float4 a0 = *(const float4*)(zs + (kk + t) * 128 + tn * 8);
                float4 a1 = *(const float4*)(zs + (kk + t) * 128 + tn * 8 + 4);
                zr[t][0] = a0.x; zr[t][1] = a0.y; zr[t][2] = a0.z; zr[t][3] = a0.w;
                zr[t][4] = a1.x; zr[t][5] = a1.y; zr[t][6] = a1.z; zr[t][7] = a1.w;
            }
            // k strictly ascending -> bit-identical to R1 sums -> exact idx
#pragma unroll
            for (int t = 0; t < 4; ++t)
#pragma unroll
                for (int a = 0; a < 8; ++a)
#pragma unroll
                    for (int b = 0; b < 8; ++b)
                        acc[a][b] = fmaf(zr[t][a], ev[b][t], acc[a][b]);
        }
    }

    // fold -0.5*||e||^2, per-thread argmax over its 8 cols
    float best[8]; int bi[8];
#pragma unroll
    for (int a = 0; a < 8; ++a) { best[a] = -3.0e38f; bi[a] = 0; }
#pragma unroll
    for (int b = 0; b < 8; ++b) {
        int j = j0 + tj * 8 + b;
        float hn = 0.5f * enorm[j];
#pragma unroll
        for (int a = 0; a < 8; ++a) {
            float s = acc[a][b] - hn;
            if (s > best[a] || (s == best[a] && j < bi[a])) { best[a] = s; bi[a] = j; }
        }
    }

    // cross-tj reduction via LDS (reuse zs)
    __syncthreads();
    float* sred = zs;                 // 2048 floats
    int*   ired = (int*)(zs + 2048);  // 2048 ints
#pragma unroll
    for (int a = 0; a < 8; ++a) { sred[tid * 8 + a] = best[a]; ired[tid * 8 + a] = bi[a]; }
    __syncthreads();
    if (tid < 128) {
        int tn_own = tid >> 3, a = tid & 7;
        float bs = -3.4e38f; int bj = 0;
        for (int t2 = 0; t2 < 16; ++t2) {
            int src = ((t2 << 4) | tn_own) * 8 + a;
            float s = sred[src];
            int jj = ired[src];
            if (s > bs || (s == bs && jj < bj)) { bs = s; bj = jj; }
        }
        score_ws[js * NVEC + n0 + tid] = bs;
        idxp_ws [js * NVEC + n0 + tid] = bj;
    }
}

// ---------------- merge the 8 j-splits ----------------
__global__ __launch_bounds__(256) void vq_merge(
    const float* __restrict__ score_ws, const int* __restrict__ idxp_ws,
    int* __restrict__ idx_ws, float* __restrict__ idx_out, int* __restrict__ hist)
{
    int n = blockIdx.x * 256 + threadIdx.x;
    float bs = -3.4e38f; int bj = 0;
#pragma unroll
    for (int s = 0; s < NSPLIT; ++s) {
        float sc = score_ws[s * NVEC + n];
        int j = idxp_ws[s * NVEC + n];
        if (sc > bs || (sc == bs && j < bj)) { bs = sc; bj = j; }
    }
    idx_ws[n] = bj;
    idx_out[n] = (float)bj;
    atomicAdd(&hist[bj], 1);
}

// ---------------- gather + outputs + loss partial sums ----------------
__global__ __launch_bounds__(256) void vq_gather(
    const float* __restrict__ z, const float* __restrict__ emb,
    const int* __restrict__ idx_ws, float* __restrict__ zq,
    float* __restrict__ zq1, double* __restrict__ loss_sum)
{
    int tid = threadIdx.x;
    size_t i0 = ((size_t)blockIdx.x * 256 + tid) * 4;
    int hw = (int)(i0 & 1023);
    int c  = (int)((i0 >> 10) & 255);
    int b  = (int)(i0 >> 18);
    int nb = (b << 10) + hw;

    float4 zv = *(const float4*)(z + i0);
    float zr[4] = { zv.x, zv.y, zv.z, zv.w };
    float q1v[4], qv[4];
    float ls = 0.f;
#pragma unroll
    for (int k = 0; k < 4; ++k) {
        int id = idx_ws[nb + k];
        float e = emb[(size_t)id * CDIM + c];
        float d = e - zr[k];
        q1v[k] = e;
        qv[k]  = zr[k] + d;       // match ref: zp + (z_q1 - zp)
        ls += d * d;
    }
#pragma unroll
    for (int k = 0; k < 4; ++k) { zq[i0 + k] = qv[k]; zq1[i0 + k] = q1v[k]; }

    for (int off = 32; off; off >>= 1) ls += __shfl_down(ls, off, 64);
    __shared__ float wred[4];
    int lane = tid & 63, wv = tid >> 6;
    if (lane == 0) wred[wv] = ls;
    __syncthreads();
    if (tid == 0) {
        float t = wred[0] + wred[1] + wred[2] + wred[3];
        atomicAdd(loss_sum, (double)t);
    }
}

// ---------------- finalize: loss scalar + perplexity ----------------
__global__ __launch_bounds__(1024) void vq_final(
    const int* __restrict__ hist, const double* __restrict__ loss_sum,
    float* __restrict__ out_loss, float* __restrict__ out_perp)
{
    int tid = threadIdx.x;
    float em = (float)hist[tid] * (1.0f / 32768.0f);
    float term = em * logf(em + 1e-10f);
    for (int off = 32; off; off >>= 1) term += __shfl_down(term, off, 64);
    __shared__ float red[16];
    int lane = tid & 63, wv = tid >> 6;
    if (lane == 0) red[wv] = term;
    __syncthreads();
    if (tid == 0) {
        float s = 0.f;
        for (int i = 0; i < 16; ++i) s += red[i];
        *out_perp = expf(-s);
        *out_loss = (float)(*loss_sum * 1.25 / 8388608.0);
    }
}

extern "C" void kernel_launch(void* const* d_in, const int* in_sizes, int n_in,
                              void* d_out, int out_size, void* d_ws, size_t ws_size,
                              hipStream_t stream) {
    const float* z   = (const float*)d_in[0];
    const float* emb = (const float*)d_in[1];
    float* out = (float*)d_out;
    char*  ws  = (char*)d_ws;

    double* loss_sum = (double*)ws;
    int*    hist     = (int*)(ws + WS_HIST);
    float*  enorm    = (float*)(ws + WS_ENORM);
    int*    idx_ws   = (int*)(ws + WS_IDX);
    float*  score_ws = (float*)(ws + WS_SCORE);
    int*    idxp_ws  = (int*)(ws + WS_IDXP);

    // zero loss accumulator + histogram (ws is poisoned 0xAA before every call)
    hipMemsetAsync(d_ws, 0, 8192, stream);

    vq_enorm <<<256, 256, 0, stream>>>(emb, enorm);
    vq_argmin<<<2048, 256, 0, stream>>>(z, emb, enorm, score_ws, idxp_ws);
    vq_merge <<<128, 256, 0, stream>>>(score_ws, idxp_ws, idx_ws, out + OUT_IDX, hist);
    vq_gather<<<8192, 256, 0, stream>>>(z, emb, idx_ws, out + OUT_ZQ, out + OUT_ZQ1, loss_sum);
    vq_final <<<1, 1024, 0, stream>>>(hist, loss_sum, out + OUT_LOSS, out + OUT_PERP);
}

// Round 3
// 347.426 us; speedup vs baseline: 1.3032x; 1.3032x over previous
//
#include <hip/hip_runtime.h>
#include <hip/hip_bf16.h>
#include <math.h>

// Problem constants
#define CDIM 256
#define HW   1024          // 32*32
#define NVEC 32768         // B*H*W
#define NE   1024
#define ZSIZE 8388608      // 32*256*32*32
#define NSPLIT 8           // codebook j-splits (128 codes each)

// Output layout (floats): [loss(1)][z_q(ZSIZE)][perp(1)][idx(NVEC)][z_q1(ZSIZE)]
#define OUT_LOSS 0
#define OUT_ZQ   1
#define OUT_PERP 8388609
#define OUT_IDX  8388610
#define OUT_ZQ1  8421378

// Workspace layout (bytes)
#define WS_HIST   64                    // 1024 ints
#define WS_ENORM  8192                  // 1024 floats
#define WS_IDX    16384                 // 32768 ints (final idx)
#define WS_SCORE  147456                // 8*32768 floats (per-split best score)
#define WS_IDXP   1196032               // 8*32768 ints  (per-split best idx)

// ---------------- codebook norms: ||e_j||^2 ----------------
__global__ __launch_bounds__(256) void vq_enorm(const float* __restrict__ emb,
                                                float* __restrict__ enorm) {
    int code = blockIdx.x * 4 + (threadIdx.x >> 6);
    int lane = threadIdx.x & 63;
    float4 v = *(const float4*)(emb + (size_t)code * CDIM + lane * 4);
    float s = v.x * v.x + v.y * v.y + v.z * v.z + v.w * v.w;
    for (int off = 32; off; off >>= 1) s += __shfl_down(s, off, 64);
    if (lane == 0) enorm[code] = s;
}

// ---------------- fused distance-GEMM + per-split argmax ----------------
// score(n,j) = z_n . e_j - 0.5*||e_j||^2  (argmax == argmin of distance)
// Block: BM=128 rows x 128-code split, BK=32, 256 threads, 8x8 micro-tile.
// launch_bounds(256,2): VGPR cap 256 so the ~150-reg working set stays live
// (R2's (256,3) let the allocator squeeze to 84 VGPRs -> 2x VALU issue).
__global__ __launch_bounds__(256, 2) void vq_argmin(
    const float* __restrict__ z, const float* __restrict__ emb,
    const float* __restrict__ enorm,
    float* __restrict__ score_ws, int* __restrict__ idxp_ws)
{
    __shared__ float zs[32 * 128];   // 16 KB, [k][n] stride 128
    __shared__ float es[128 * 32];   // 16 KB, [j][k] stride 32 (swizzled k-quads)

    const int tid = threadIdx.x;
    const int tn  = tid & 15;        // rows tn*8 .. tn*8+7
    const int tj  = tid >> 4;        // cols tj*8 .. tj*8+7
    const int mtile = blockIdx.x & 255;
    const int js    = blockIdx.x >> 8;          // 0..7
    const int n0 = mtile << 7;                  // 128-row tile (never crosses image)
    const int b_img = n0 >> 10, hw0 = n0 & 1023;
    const float* zb = z + (size_t)b_img * (CDIM * HW) + hw0;
    const int j0 = js << 7;
    const int swz = tj & 7;

    float acc[8][8];
#pragma unroll
    for (int a = 0; a < 8; ++a)
#pragma unroll
        for (int b = 0; b < 8; ++b) acc[a][b] = 0.f;

    for (int k0 = 0; k0 < CDIM; k0 += 32) {
        __syncthreads();
        // stage z tile: 32 k-rows x 128 n (coalesced, contiguous LDS writes)
#pragma unroll
        for (int r = 0; r < 4; ++r) {
            int u = r * 256 + tid;
            int krow = u >> 5;          // 0..31
            int c4   = u & 31;          // float4 col
            float4 v = *(const float4*)(zb + (size_t)(k0 + krow) * HW + c4 * 4);
            *(float4*)(zs + krow * 128 + c4 * 4) = v;
        }
        // stage e tile: 128 j x 32 k, row-major, swizzled k-quad within row
#pragma unroll
        for (int r = 0; r < 4; ++r) {
            int u = r * 256 + tid;
            int j  = u >> 3;            // 0..127
            int c4 = u & 7;             // k-quad
            float4 v = *(const float4*)(emb + (size_t)(j0 + j) * CDIM + k0 + c4 * 4);
            *(float4*)(es + j * 32 + ((c4 ^ ((j >> 3) & 7)) << 2)) = v;
        }
        __syncthreads();

#pragma unroll 2
        for (int kk = 0; kk < 32; kk += 4) {
            const int eoff = (((kk >> 2) ^ swz) << 2);
            float ev[8][4];
#pragma unroll
            for (int b = 0; b < 8; ++b) {
                float4 v = *(const float4*)(es + (tj * 8 + b) * 32 + eoff);
                ev[b][0] = v.x; ev[b][1] = v.y; ev[b][2] = v.z; ev[b][3] = v.w;
            }
            float zr[4][8];
#pragma unroll
            for (int t = 0; t < 4; ++t) {
                float4 a0 = *(const float4*)(zs + (kk + t) * 128 + tn * 8);
                float4 a1 = *(const float4*)(zs + (kk + t) * 128 + tn * 8 + 4);
                zr[t][0] = a0.x; zr[t][1] = a0.y; zr[t][2] = a0.z; zr[t][3] = a0.w;
                zr[t][4] = a1.x; zr[t][5] = a1.y; zr[t][6] = a1.z; zr[t][7] = a1.w;
            }
            // k strictly ascending -> bit-identical to R1/R2 sums -> exact idx
#pragma unroll
            for (int t = 0; t < 4; ++t)
#pragma unroll
                for (int a = 0; a < 8; ++a)
#pragma unroll
                    for (int b = 0; b < 8; ++b)
                        acc[a][b] = fmaf(zr[t][a], ev[b][t], acc[a][b]);
        }
    }

    // fold -0.5*||e||^2, per-thread argmax over its 8 cols
    float best[8]; int bi[8];
#pragma unroll
    for (int a = 0; a < 8; ++a) { best[a] = -3.0e38f; bi[a] = 0; }
#pragma unroll
    for (int b = 0; b < 8; ++b) {
        int j = j0 + tj * 8 + b;
        float hn = 0.5f * enorm[j];
#pragma unroll
        for (int a = 0; a < 8; ++a) {
            float s = acc[a][b] - hn;
            if (s > best[a] || (s == best[a] && j < bi[a])) { best[a] = s; bi[a] = j; }
        }
    }

    // cross-tj reduction via LDS (reuse zs)
    __syncthreads();
    float* sred = zs;                 // 2048 floats
    int*   ired = (int*)(zs + 2048);  // 2048 ints
#pragma unroll
    for (int a = 0; a < 8; ++a) { sred[tid * 8 + a] = best[a]; ired[tid * 8 + a] = bi[a]; }
    __syncthreads();
    if (tid < 128) {
        int tn_own = tid >> 3, a = tid & 7;
        float bs = -3.4e38f; int bj = 0;
        for (int t2 = 0; t2 < 16; ++t2) {
            int src = ((t2 << 4) | tn_own) * 8 + a;
            float s = sred[src];
            int jj = ired[src];
            if (s > bs || (s == bs && jj < bj)) { bs = s; bj = jj; }
        }
        score_ws[js * NVEC + n0 + tid] = bs;
        idxp_ws [js * NVEC + n0 + tid] = bj;
    }
}

// ---------------- merge the 8 j-splits ----------------
__global__ __launch_bounds__(256) void vq_merge(
    const float* __restrict__ score_ws, const int* __restrict__ idxp_ws,
    int* __restrict__ idx_ws, float* __restrict__ idx_out, int* __restrict__ hist)
{
    int n = blockIdx.x * 256 + threadIdx.x;
    float bs = -3.4e38f; int bj = 0;
#pragma unroll
    for (int s = 0; s < NSPLIT; ++s) {
        float sc = score_ws[s * NVEC + n];
        int j = idxp_ws[s * NVEC + n];
        if (sc > bs || (sc == bs && j < bj)) { bs = sc; bj = j; }
    }
    idx_ws[n] = bj;
    idx_out[n] = (float)bj;
    atomicAdd(&hist[bj], 1);
}

// ---------------- gather + outputs + loss (LDS-staged codebook rows) ----------------
// Block = 64 consecutive n (one hw-stripe of one image). Stage the 64 selected
// emb rows into LDS ONCE via coalesced float4 reads (kills the 33.5M random
// 4B gathers of R2). Rows padded to 257 floats: per-c read es[lane*257+c]
// has bank (lane+c)%32 -> 2 lanes/bank = free.
__global__ __launch_bounds__(256) void vq_gather(
    const float* __restrict__ z, const float* __restrict__ emb,
    const int* __restrict__ idx_ws, float* __restrict__ zq,
    float* __restrict__ zq1, double* __restrict__ loss_sum)
{
    __shared__ float es[64 * 257];   // 65792 B
    __shared__ int ids[64];
    __shared__ float wred[4];

    const int tid  = threadIdx.x;
    const int lane = tid & 63;
    const int wv   = tid >> 6;       // 0..3
    const int blk  = blockIdx.x;     // 0..511
    const int b    = blk >> 4;       // image 0..31
    const int hw0  = (blk & 15) << 6;
    const int n0   = (b << 10) + hw0;

    if (tid < 64) ids[tid] = idx_ws[n0 + tid];
    __syncthreads();

    // stage 64 emb rows; wave wv stages rows wv, wv+4, ... (coalesced 1KB/row)
    for (int r = wv; r < 64; r += 4) {
        const float* er = emb + (size_t)ids[r] * CDIM;
        float4 v = *(const float4*)(er + lane * 4);
        *(float4*)(&es[r * 257 + lane * 4]) = v;
    }
    __syncthreads();

    const size_t zbase = (size_t)b * (CDIM * HW) + hw0;
    float ls = 0.f;
    for (int c = wv; c < CDIM; c += 4) {
        size_t off = zbase + (size_t)c * HW + lane;   // coalesced 256B per wave
        float zv = z[off];
        float e  = es[lane * 257 + c];
        float d  = e - zv;
        zq[off]  = zv + d;     // match ref: zp + (z_q1 - zp)
        zq1[off] = e;
        ls += d * d;
    }

    for (int off = 32; off; off >>= 1) ls += __shfl_down(ls, off, 64);
    if (lane == 0) wred[wv] = ls;
    __syncthreads();
    if (tid == 0)
        atomicAdd(loss_sum, (double)(wred[0] + wred[1] + wred[2] + wred[3]));
}

// ---------------- finalize: loss scalar + perplexity ----------------
__global__ __launch_bounds__(1024) void vq_final(
    const int* __restrict__ hist, const double* __restrict__ loss_sum,
    float* __restrict__ out_loss, float* __restrict__ out_perp)
{
    int tid = threadIdx.x;
    float em = (float)hist[tid] * (1.0f / 32768.0f);
    float term = em * logf(em + 1e-10f);
    for (int off = 32; off; off >>= 1) term += __shfl_down(term, off, 64);
    __shared__ float red[16];
    int lane = tid & 63, wv = tid >> 6;
    if (lane == 0) red[wv] = term;
    __syncthreads();
    if (tid == 0) {
        float s = 0.f;
        for (int i = 0; i < 16; ++i) s += red[i];
        *out_perp = expf(-s);
        *out_loss = (float)(*loss_sum * 1.25 / 8388608.0);
    }
}

extern "C" void kernel_launch(void* const* d_in, const int* in_sizes, int n_in,
                              void* d_out, int out_size, void* d_ws, size_t ws_size,
                              hipStream_t stream) {
    const float* z   = (const float*)d_in[0];
    const float* emb = (const float*)d_in[1];
    float* out = (float*)d_out;
    char*  ws  = (char*)d_ws;

    double* loss_sum = (double*)ws;
    int*    hist     = (int*)(ws + WS_HIST);
    float*  enorm    = (float*)(ws + WS_ENORM);
    int*    idx_ws   = (int*)(ws + WS_IDX);
    float*  score_ws = (float*)(ws + WS_SCORE);
    int*    idxp_ws  = (int*)(ws + WS_IDXP);

    // zero loss accumulator + histogram (ws is poisoned 0xAA before every call)
    hipMemsetAsync(d_ws, 0, 8192, stream);

    vq_enorm <<<256, 256, 0, stream>>>(emb, enorm);
    vq_argmin<<<2048, 256, 0, stream>>>(z, emb, enorm, score_ws, idxp_ws);
    vq_merge <<<128, 256, 0, stream>>>(score_ws, idxp_ws, idx_ws, out + OUT_IDX, hist);
    vq_gather<<<512, 256, 0, stream>>>(z, emb, idx_ws, out + OUT_ZQ, out + OUT_ZQ1, loss_sum);
    vq_final <<<1, 1024, 0, stream>>>(hist, loss_sum, out + OUT_LOSS, out + OUT_PERP);
}